// Round 6
// baseline (868.438 us; speedup 1.0000x reference)
//
#include <hip/hip_runtime.h>
#include <hip/hip_bf16.h>
#include <stdint.h>

#define NN 100000      // nodes
#define NE 1600000     // edges
#define INF 256        // in feats
#define HF 128         // hidden feats
#define NC 40          // classes
#define NNP 100352     // NN padded to multiple of 512
#define NB (NNP / 512) // 196 scan blocks

typedef unsigned short ushort_t;
typedef unsigned int uint_t;

__device__ __forceinline__ float bflo(uint_t u) {
    union { uint_t i; float f; } v; v.i = u << 16; return v.f;
}
__device__ __forceinline__ float bfhi(uint_t u) {
    union { uint_t i; float f; } v; v.i = u & 0xffff0000u; return v.f;
}
__device__ __forceinline__ uint_t f2bf(float f) {
    __hip_bfloat16 h = __float2bfloat16(f);
    return (uint_t)*reinterpret_cast<ushort_t*>(&h);
}

// ---- degree histograms ----
__global__ void k_deg(const int* __restrict__ src, const int* __restrict__ dst,
                      int* __restrict__ cs, int* __restrict__ cd) {
    int i = blockIdx.x * 256 + threadIdx.x;
    if (i < NE) {
        atomicAdd(&cs[src[i]], 1);
        atomicAdd(&cd[dst[i]], 1);
    }
}

// ---- counts -> rsqrt(max(deg,1)) ----
__global__ void k_isqrt(const int* __restrict__ cs, const int* __restrict__ cd,
                        float* __restrict__ isq_s, float* __restrict__ isq_d) {
    int i = blockIdx.x * 256 + threadIdx.x;
    if (i < NN) {
        isq_s[i] = rsqrtf(fmaxf((float)cs[i], 1.0f));
        isq_d[i] = rsqrtf(fmaxf((float)cd[i], 1.0f));
    }
}

// ---- scan phase A: per-block sums of cd ----
__global__ void k_scanA(const int* __restrict__ cd, int* __restrict__ blk) {
    __shared__ int s[512];
    int i = blockIdx.x * 512 + threadIdx.x;
    s[threadIdx.x] = (i < NN) ? cd[i] : 0;
    __syncthreads();
    for (int off = 256; off > 0; off >>= 1) {
        if (threadIdx.x < (unsigned)off) s[threadIdx.x] += s[threadIdx.x + off];
        __syncthreads();
    }
    if (threadIdx.x == 0) blk[blockIdx.x] = s[0];
}

// ---- scan phase B: exclusive scan of block sums ----
__global__ void k_scanB(int* __restrict__ blk) {
    if (threadIdx.x == 0) {
        int run = 0;
        for (int b = 0; b < NB; ++b) { int t = blk[b]; blk[b] = run; run += t; }
    }
}

// ---- scan phase C: block inclusive scan -> row_ptr (exclusive), cursor ----
__global__ void k_scanC(const int* __restrict__ cd, const int* __restrict__ blk,
                        int* __restrict__ row_ptr, int* __restrict__ cursor) {
    __shared__ int s[512];
    int i = blockIdx.x * 512 + threadIdx.x;
    int v = (i < NN) ? cd[i] : 0;
    s[threadIdx.x] = v;
    __syncthreads();
    for (int off = 1; off < 512; off <<= 1) {
        int t = 0;
        if (threadIdx.x >= (unsigned)off) t = s[threadIdx.x - off];
        __syncthreads();
        s[threadIdx.x] += t;
        __syncthreads();
    }
    int rp = blk[blockIdx.x] + s[threadIdx.x] - v;  // exclusive prefix
    row_ptr[i] = rp;      // row_ptr[NN] == NE
    cursor[i] = rp;
}

// ---- counting-sort fill: src ids grouped by dst ----
__global__ void k_fill(const int* __restrict__ src, const int* __restrict__ dst,
                       int* __restrict__ cursor, int* __restrict__ srcs) {
    int e = blockIdx.x * 256 + threadIdx.x;
    if (e < NE) {
        int d = dst[e];
        int pos = atomicAdd(&cursor[d], 1);
        srcs[pos] = src[e];
    }
}

// ---- GEMM1: H[N,128](bf16) = (X[N,256]fp32 @ W1[256,128]fp32) * isq_s[row] ----
// W1 staged in 4 chunks of 64 K-rows (32 KB LDS).
__launch_bounds__(256)
__global__ void k_gemm1(const float* __restrict__ X, const float* __restrict__ W1,
                        const float* __restrict__ isq_s, ushort_t* __restrict__ H) {
    __shared__ float wl[64 * HF];   // 32 KB chunk of W1

    const int col_t = threadIdx.x & 15;
    const int row_t = threadIdx.x >> 4;
    const int c0 = col_t * 8;
    const int r0 = blockIdx.x * 64 + row_t * 4;

    float acc[4][8];
#pragma unroll
    for (int i = 0; i < 4; i++)
#pragma unroll
        for (int j = 0; j < 8; j++) acc[i][j] = 0.0f;

    int rr[4];
#pragma unroll
    for (int i = 0; i < 4; i++) rr[i] = min(r0 + i, NN - 1);

    for (int ch = 0; ch < 4; ++ch) {
        const float4* wg = (const float4*)(W1 + (size_t)ch * 64 * HF);
        for (int t = threadIdx.x; t < 64 * HF / 4; t += 256)
            ((float4*)wl)[t] = wg[t];
        __syncthreads();

        for (int k0 = 0; k0 < 64; k0 += 8) {
            float xf[4][8];
#pragma unroll
            for (int i = 0; i < 4; i++) {
                const float* xp = &X[(size_t)rr[i] * INF + ch * 64 + k0];
                float4 a = *(const float4*)xp;
                float4 b = *(const float4*)(xp + 4);
                xf[i][0] = a.x; xf[i][1] = a.y; xf[i][2] = a.z; xf[i][3] = a.w;
                xf[i][4] = b.x; xf[i][5] = b.y; xf[i][6] = b.z; xf[i][7] = b.w;
            }
#pragma unroll
            for (int kk = 0; kk < 8; kk++) {
                const float* wp = &wl[(k0 + kk) * HF + c0];
                float4 wa = *(const float4*)wp;
                float4 wb = *(const float4*)(wp + 4);
                float wf[8] = { wa.x, wa.y, wa.z, wa.w, wb.x, wb.y, wb.z, wb.w };
#pragma unroll
                for (int i = 0; i < 4; i++)
#pragma unroll
                    for (int j = 0; j < 8; j++)
                        acc[i][j] += xf[i][kk] * wf[j];
            }
        }
        __syncthreads();
    }

#pragma unroll
    for (int i = 0; i < 4; i++) {
        int r = r0 + i;
        if (r < NN) {
            float s = isq_s[r];
            uint_t w0 = f2bf(acc[i][0] * s) | (f2bf(acc[i][1] * s) << 16);
            uint_t w1 = f2bf(acc[i][2] * s) | (f2bf(acc[i][3] * s) << 16);
            uint_t w2 = f2bf(acc[i][4] * s) | (f2bf(acc[i][5] * s) << 16);
            uint_t w3 = f2bf(acc[i][6] * s) | (f2bf(acc[i][7] * s) << 16);
            uint4 o = { w0, w1, w2, w3 };
            *(uint4*)&H[(size_t)r * HF + c0] = o;
        }
    }
}

// ---- fused layer1-aggregate + layer2 GEMM ----
// per node n: m = sum_{e:dst=n} H[src_e]; h1 = relu(m*isq_d[n] + b1) -> LDS;
// H2[n,c] = (h1 . W2[:,c]) * isq_s[n], fp32.  One wave per node.
__launch_bounds__(256)
__global__ void k_agg1_gemm2(const int* __restrict__ row_ptr, const int* __restrict__ srcs,
                             const uint_t* __restrict__ H32, const float* __restrict__ isq_d,
                             const float* __restrict__ isq_s, const float* __restrict__ b1,
                             const float* __restrict__ W2, float* __restrict__ H2) {
    __shared__ float w2s[HF * NC];   // 20 KB fp32
    __shared__ float h1s[4][HF];     // 2 KB, one slice per wave
    for (int t = threadIdx.x; t < HF * NC; t += 256) w2s[t] = W2[t];

    const int wv = threadIdx.x >> 6;
    const int lane = threadIdx.x & 63;
    const int n = blockIdx.x * 4 + wv;

    if (n < NN) {
        int beg = row_ptr[n], end = row_ptr[n + 1];
        float a0 = 0.0f, a1 = 0.0f;
        for (int j = beg; j < end; ++j) {
            uint_t v = H32[(size_t)srcs[j] * 64 + lane];
            a0 += bflo(v);
            a1 += bfhi(v);
        }
        float sc = isq_d[n];
        float2 bv = ((const float2*)b1)[lane];
        h1s[wv][lane * 2]     = fmaxf(a0 * sc + bv.x, 0.0f);
        h1s[wv][lane * 2 + 1] = fmaxf(a1 * sc + bv.y, 0.0f);
    }
    __syncthreads();   // uniform: covers W2 staging + h1 slices

    if (n < NN && lane < NC) {
        float acc = 0.0f;
#pragma unroll 8
        for (int k = 0; k < HF; ++k)
            acc += h1s[wv][k] * w2s[k * NC + lane];
        H2[(size_t)n * NC + lane] = acc * isq_s[n];
    }
}

// ---- gather2: out[n] = fp32( (sum_{e:dst=n} H2[src_e]) * isq_d[n] + b2 ) ----
__global__ void k_gather2(const int* __restrict__ row_ptr, const int* __restrict__ srcs,
                          const float* __restrict__ H2, const float* __restrict__ isq_d,
                          const float* __restrict__ b2, float* __restrict__ out) {
    int n = blockIdx.x * 4 + (threadIdx.x >> 6);
    int lane = threadIdx.x & 63;
    if (n >= NN || lane >= NC) return;
    int beg = row_ptr[n], end = row_ptr[n + 1];
    float a = 0.0f;
    for (int j = beg; j < end; ++j)
        a += H2[(size_t)srcs[j] * NC + lane];
    out[(size_t)n * NC + lane] = a * isq_d[n] + b2[lane];
}

extern "C" void kernel_launch(void* const* d_in, const int* in_sizes, int n_in,
                              void* d_out, int out_size, void* d_ws, size_t ws_size,
                              hipStream_t stream) {
    const float* X  = (const float*)d_in[0];
    const int* src  = (const int*)d_in[1];
    const int* dst  = (const int*)d_in[2];
    const float* W1 = (const float*)d_in[3];
    const float* b1 = (const float*)d_in[4];
    const float* W2 = (const float*)d_in[5];
    const float* b2 = (const float*)d_in[6];
    float* out = (float*)d_out;

    // workspace layout in 4-byte words; peak = 12,502,272 words = 47.7 MiB
    int* w = (int*)d_ws;
    int* cs        = w;                         // NNP  (reused as cursor)
    int* cd        = w + NNP;                   // NNP
    float* isq_s   = (float*)(w + 2 * NNP);     // NNP
    float* isq_d   = (float*)(w + 3 * NNP);     // NNP
    int* row_ptr   = w + 4 * NNP;               // NNP (row_ptr[NN] valid)
    int* blk       = w + 5 * NNP;               // 512
    int* srcs      = w + 5 * NNP + 512;         // NE
    ushort_t* H    = (ushort_t*)(w + 5 * NNP + 512 + NE);        // N*128 bf16 (6.4M words)
    float* H2      = (float*)(w + 5 * NNP + 512 + NE + 6400000); // N*40 fp32 (4M words)
    int* cursor    = cs;                        // alias: cs consumed by k_isqrt

    hipMemsetAsync(cs, 0, 2 * NNP * sizeof(int), stream);

    // CSR build (dst-grouped)
    k_deg  <<<(NE + 255) / 256, 256, 0, stream>>>(src, dst, cs, cd);
    k_isqrt<<<(NN + 255) / 256, 256, 0, stream>>>(cs, cd, isq_s, isq_d);
    k_scanA<<<NB, 512, 0, stream>>>(cd, blk);
    k_scanB<<<1, 64, 0, stream>>>(blk);
    k_scanC<<<NB, 512, 0, stream>>>(cd, blk, row_ptr, cursor);
    k_fill <<<(NE + 255) / 256, 256, 0, stream>>>(src, dst, cursor, srcs);

    // layer 1 GEMM
    k_gemm1<<<(NN + 63) / 64, 256, 0, stream>>>(X, W1, isq_s, H);

    // fused: layer-1 aggregate + bias/relu + layer-2 GEMM
    k_agg1_gemm2<<<(NN + 3) / 4, 256, 0, stream>>>(row_ptr, srcs, (const uint_t*)H,
                                                   isq_d, isq_s, b1, W2, H2);

    // layer-2 aggregate + bias -> fp32 out
    k_gather2<<<(NN + 3) / 4, 256, 0, stream>>>(row_ptr, srcs, H2, isq_d, b2, out);
}

// Round 7
// 700.572 us; speedup vs baseline: 1.2396x; 1.2396x over previous
//
#include <hip/hip_runtime.h>
#include <hip/hip_bf16.h>
#include <stdint.h>

#define NN 100000      // nodes
#define NE 1600000     // edges
#define INF 256        // in feats
#define HF 128         // hidden feats
#define NC 40          // classes
#define NNP 100352     // NN padded to multiple of 512
#define NB (NNP / 512) // 196 scan blocks

typedef unsigned short ushort_t;
typedef unsigned int uint_t;

__device__ __forceinline__ float bflo(uint_t u) {
    union { uint_t i; float f; } v; v.i = u << 16; return v.f;
}
__device__ __forceinline__ float bfhi(uint_t u) {
    union { uint_t i; float f; } v; v.i = u & 0xffff0000u; return v.f;
}
__device__ __forceinline__ uint_t f2bf(float f) {
    __hip_bfloat16 h = __float2bfloat16(f);
    return (uint_t)*reinterpret_cast<ushort_t*>(&h);
}

// ---- degree histograms ----
__global__ void k_deg(const int* __restrict__ src, const int* __restrict__ dst,
                      int* __restrict__ cs, int* __restrict__ cd) {
    int i = blockIdx.x * 256 + threadIdx.x;
    if (i < NE) {
        atomicAdd(&cs[src[i]], 1);
        atomicAdd(&cd[dst[i]], 1);
    }
}

// ---- counts -> rsqrt(max(deg,1)) ----
__global__ void k_isqrt(const int* __restrict__ cs, const int* __restrict__ cd,
                        float* __restrict__ isq_s, float* __restrict__ isq_d) {
    int i = blockIdx.x * 256 + threadIdx.x;
    if (i < NN) {
        isq_s[i] = rsqrtf(fmaxf((float)cs[i], 1.0f));
        isq_d[i] = rsqrtf(fmaxf((float)cd[i], 1.0f));
    }
}

// ---- scan phase A: per-block sums of cd ----
__global__ void k_scanA(const int* __restrict__ cd, int* __restrict__ blk) {
    __shared__ int s[512];
    int i = blockIdx.x * 512 + threadIdx.x;
    s[threadIdx.x] = (i < NN) ? cd[i] : 0;
    __syncthreads();
    for (int off = 256; off > 0; off >>= 1) {
        if (threadIdx.x < (unsigned)off) s[threadIdx.x] += s[threadIdx.x + off];
        __syncthreads();
    }
    if (threadIdx.x == 0) blk[blockIdx.x] = s[0];
}

// ---- scan phase B: exclusive scan of block sums ----
__global__ void k_scanB(int* __restrict__ blk) {
    if (threadIdx.x == 0) {
        int run = 0;
        for (int b = 0; b < NB; ++b) { int t = blk[b]; blk[b] = run; run += t; }
    }
}

// ---- scan phase C: block inclusive scan -> row_ptr (exclusive), cursor ----
__global__ void k_scanC(const int* __restrict__ cd, const int* __restrict__ blk,
                        int* __restrict__ row_ptr, int* __restrict__ cursor) {
    __shared__ int s[512];
    int i = blockIdx.x * 512 + threadIdx.x;
    int v = (i < NN) ? cd[i] : 0;
    s[threadIdx.x] = v;
    __syncthreads();
    for (int off = 1; off < 512; off <<= 1) {
        int t = 0;
        if (threadIdx.x >= (unsigned)off) t = s[threadIdx.x - off];
        __syncthreads();
        s[threadIdx.x] += t;
        __syncthreads();
    }
    int rp = blk[blockIdx.x] + s[threadIdx.x] - v;  // exclusive prefix
    row_ptr[i] = rp;      // row_ptr[NN] == NE
    cursor[i] = rp;
}

// ---- counting-sort fill: src ids grouped by dst ----
__global__ void k_fill(const int* __restrict__ src, const int* __restrict__ dst,
                       int* __restrict__ cursor, int* __restrict__ srcs) {
    int e = blockIdx.x * 256 + threadIdx.x;
    if (e < NE) {
        int d = dst[e];
        int pos = atomicAdd(&cursor[d], 1);
        srcs[pos] = src[e];
    }
}

// ---- GEMM1: H[N,128](bf16) = (X[N,256]fp32 @ W1[256,128]fp32) * isq_s[row] ----
__launch_bounds__(256)
__global__ void k_gemm1(const float* __restrict__ X, const float* __restrict__ W1,
                        const float* __restrict__ isq_s, ushort_t* __restrict__ H) {
    __shared__ float wl[64 * HF];   // 32 KB chunk of W1

    const int col_t = threadIdx.x & 15;
    const int row_t = threadIdx.x >> 4;
    const int c0 = col_t * 8;
    const int r0 = blockIdx.x * 64 + row_t * 4;

    float acc[4][8];
#pragma unroll
    for (int i = 0; i < 4; i++)
#pragma unroll
        for (int j = 0; j < 8; j++) acc[i][j] = 0.0f;

    int rr[4];
#pragma unroll
    for (int i = 0; i < 4; i++) rr[i] = min(r0 + i, NN - 1);

    for (int ch = 0; ch < 4; ++ch) {
        const float4* wg = (const float4*)(W1 + (size_t)ch * 64 * HF);
        for (int t = threadIdx.x; t < 64 * HF / 4; t += 256)
            ((float4*)wl)[t] = wg[t];
        __syncthreads();

        for (int k0 = 0; k0 < 64; k0 += 8) {
            float xf[4][8];
#pragma unroll
            for (int i = 0; i < 4; i++) {
                const float* xp = &X[(size_t)rr[i] * INF + ch * 64 + k0];
                float4 a = *(const float4*)xp;
                float4 b = *(const float4*)(xp + 4);
                xf[i][0] = a.x; xf[i][1] = a.y; xf[i][2] = a.z; xf[i][3] = a.w;
                xf[i][4] = b.x; xf[i][5] = b.y; xf[i][6] = b.z; xf[i][7] = b.w;
            }
#pragma unroll
            for (int kk = 0; kk < 8; kk++) {
                const float* wp = &wl[(k0 + kk) * HF + c0];
                float4 wa = *(const float4*)wp;
                float4 wb = *(const float4*)(wp + 4);
                float wf[8] = { wa.x, wa.y, wa.z, wa.w, wb.x, wb.y, wb.z, wb.w };
#pragma unroll
                for (int i = 0; i < 4; i++)
#pragma unroll
                    for (int j = 0; j < 8; j++)
                        acc[i][j] += xf[i][kk] * wf[j];
            }
        }
        __syncthreads();
    }

#pragma unroll
    for (int i = 0; i < 4; i++) {
        int r = r0 + i;
        if (r < NN) {
            float s = isq_s[r];
            uint_t w0 = f2bf(acc[i][0] * s) | (f2bf(acc[i][1] * s) << 16);
            uint_t w1 = f2bf(acc[i][2] * s) | (f2bf(acc[i][3] * s) << 16);
            uint_t w2 = f2bf(acc[i][4] * s) | (f2bf(acc[i][5] * s) << 16);
            uint_t w3 = f2bf(acc[i][6] * s) | (f2bf(acc[i][7] * s) << 16);
            uint4 o = { w0, w1, w2, w3 };
            *(uint4*)&H[(size_t)r * HF + c0] = o;
        }
    }
}

// ---- fused layer1-aggregate + layer2 GEMM, edge loop unrolled x4 for MLP ----
__launch_bounds__(256)
__global__ void k_agg1_gemm2(const int* __restrict__ row_ptr, const int* __restrict__ srcs,
                             const uint_t* __restrict__ H32, const float* __restrict__ isq_d,
                             const float* __restrict__ isq_s, const float* __restrict__ b1,
                             const float* __restrict__ W2, float* __restrict__ H2) {
    __shared__ float w2s[HF * NC];   // 20 KB fp32
    __shared__ float h1s[4][HF];     // 2 KB, one slice per wave
    for (int t = threadIdx.x; t < HF * NC; t += 256) w2s[t] = W2[t];

    const int wv = threadIdx.x >> 6;
    const int lane = threadIdx.x & 63;
    const int n = blockIdx.x * 4 + wv;

    if (n < NN) {
        int beg = row_ptr[n], end = row_ptr[n + 1];
        float a0 = 0.0f, a1 = 0.0f;
        int j = beg;
        for (; j + 4 <= end; j += 4) {
            int s0 = srcs[j], s1 = srcs[j + 1], s2 = srcs[j + 2], s3 = srcs[j + 3];
            uint_t v0 = H32[(size_t)s0 * 64 + lane];
            uint_t v1 = H32[(size_t)s1 * 64 + lane];
            uint_t v2 = H32[(size_t)s2 * 64 + lane];
            uint_t v3 = H32[(size_t)s3 * 64 + lane];
            a0 += bflo(v0) + bflo(v1) + bflo(v2) + bflo(v3);
            a1 += bfhi(v0) + bfhi(v1) + bfhi(v2) + bfhi(v3);
        }
        for (; j < end; ++j) {
            uint_t v = H32[(size_t)srcs[j] * 64 + lane];
            a0 += bflo(v);
            a1 += bfhi(v);
        }
        float sc = isq_d[n];
        float2 bv = ((const float2*)b1)[lane];
        h1s[wv][lane * 2]     = fmaxf(a0 * sc + bv.x, 0.0f);
        h1s[wv][lane * 2 + 1] = fmaxf(a1 * sc + bv.y, 0.0f);
    }
    __syncthreads();   // uniform: covers W2 staging + h1 slices

    if (n < NN && lane < NC) {
        float acc = 0.0f;
#pragma unroll 8
        for (int k = 0; k < HF; ++k)
            acc += h1s[wv][k] * w2s[k * NC + lane];
        H2[(size_t)n * NC + lane] = acc * isq_s[n];
    }
}

// ---- gather2: out = (segsum H2) * isq_d + b2, edge loop unrolled x4 ----
__global__ void k_gather2(const int* __restrict__ row_ptr, const int* __restrict__ srcs,
                          const float* __restrict__ H2, const float* __restrict__ isq_d,
                          const float* __restrict__ b2, float* __restrict__ out) {
    int n = blockIdx.x * 4 + (threadIdx.x >> 6);
    int lane = threadIdx.x & 63;
    if (n >= NN || lane >= NC) return;
    int beg = row_ptr[n], end = row_ptr[n + 1];
    float a = 0.0f;
    int j = beg;
    for (; j + 4 <= end; j += 4) {
        int s0 = srcs[j], s1 = srcs[j + 1], s2 = srcs[j + 2], s3 = srcs[j + 3];
        float f0 = H2[(size_t)s0 * NC + lane];
        float f1 = H2[(size_t)s1 * NC + lane];
        float f2 = H2[(size_t)s2 * NC + lane];
        float f3 = H2[(size_t)s3 * NC + lane];
        a += f0 + f1 + f2 + f3;
    }
    for (; j < end; ++j)
        a += H2[(size_t)srcs[j] * NC + lane];
    out[(size_t)n * NC + lane] = a * isq_d[n] + b2[lane];
}

extern "C" void kernel_launch(void* const* d_in, const int* in_sizes, int n_in,
                              void* d_out, int out_size, void* d_ws, size_t ws_size,
                              hipStream_t stream) {
    const float* X  = (const float*)d_in[0];
    const int* src  = (const int*)d_in[1];
    const int* dst  = (const int*)d_in[2];
    const float* W1 = (const float*)d_in[3];
    const float* b1 = (const float*)d_in[4];
    const float* W2 = (const float*)d_in[5];
    const float* b2 = (const float*)d_in[6];
    float* out = (float*)d_out;

    // workspace layout in 4-byte words; peak = 12,502,272 words = 47.7 MiB
    int* w = (int*)d_ws;
    int* cs        = w;                         // NNP  (reused as cursor)
    int* cd        = w + NNP;                   // NNP
    float* isq_s   = (float*)(w + 2 * NNP);     // NNP
    float* isq_d   = (float*)(w + 3 * NNP);     // NNP
    int* row_ptr   = w + 4 * NNP;               // NNP (row_ptr[NN] valid)
    int* blk       = w + 5 * NNP;               // 512
    int* srcs      = w + 5 * NNP + 512;         // NE
    ushort_t* H    = (ushort_t*)(w + 5 * NNP + 512 + NE);        // N*128 bf16 (6.4M words)
    float* H2      = (float*)(w + 5 * NNP + 512 + NE + 6400000); // N*40 fp32 (4M words)
    int* cursor    = cs;                        // alias: cs consumed by k_isqrt

    hipMemsetAsync(cs, 0, 2 * NNP * sizeof(int), stream);

    // CSR build (dst-grouped)
    k_deg  <<<(NE + 255) / 256, 256, 0, stream>>>(src, dst, cs, cd);
    k_isqrt<<<(NN + 255) / 256, 256, 0, stream>>>(cs, cd, isq_s, isq_d);
    k_scanA<<<NB, 512, 0, stream>>>(cd, blk);
    k_scanB<<<1, 64, 0, stream>>>(blk);
    k_scanC<<<NB, 512, 0, stream>>>(cd, blk, row_ptr, cursor);
    k_fill <<<(NE + 255) / 256, 256, 0, stream>>>(src, dst, cursor, srcs);

    // layer 1 GEMM
    k_gemm1<<<(NN + 63) / 64, 256, 0, stream>>>(X, W1, isq_s, H);

    // fused: layer-1 aggregate + bias/relu + layer-2 GEMM
    k_agg1_gemm2<<<(NN + 3) / 4, 256, 0, stream>>>(row_ptr, srcs, (const uint_t*)H,
                                                   isq_d, isq_s, b1, W2, H2);

    // layer-2 aggregate + bias -> fp32 out
    k_gather2<<<(NN + 3) / 4, 256, 0, stream>>>(row_ptr, srcs, H2, isq_d, b2, out);
}